// Round 8
// baseline (335.135 us; speedup 1.0000x reference)
//
#include <hip/hip_runtime.h>

typedef unsigned int uint32;
typedef unsigned long long uint64;
typedef float floatx2 __attribute__((ext_vector_type(2)));

#define ROWS_R 2000
#define COLS_R 20000
#define NBLK   256
#define NTHR   1024
#define NWAVE  16
#define CPB    80          /* columns per block: 250 blocks cover 20000; 250..255 all-pad */
#define CSTR   501         /* LDS column stride in dwords (2004 B): 500 data + 1 zero pad */
#define KDW    (CPB*CSTR)  /* 40080 dwords = 160320 B */
#define KGUARD 16          /* zero guard so col-pass tail reads (d<=511) stay in-bounds */
#define USLOTS 101         /* rotating u buffers: slot t = u(t); never re-read a stale line */

static constexpr float A_MARG = 1.0f / 2000.0f;
static constexpr float B_MARG = 1.0f / 20000.0f;
static constexpr float EPSV   = 1e-16f;
static constexpr float THR    = 0.005f;
static constexpr float NALPHA = -20.0f;

// ---- agent-scope (device-coherent) access helpers: bypass the non-coherent L2 ----
// Writer drains vmcnt(0) BEFORE the barrier arrival; reader loads only AFTER the
// barrier. u READS use plain cached loads (write-once rotating slots, r7 win).
// P2 reads stay agent-scope: its addresses are reused every iteration, so a
// cached line could be stale.
__device__ __forceinline__ void st_dev_f32(float* p, float v) {
    __hip_atomic_store(p, v, __ATOMIC_RELAXED, __HIP_MEMORY_SCOPE_AGENT);
}
__device__ __forceinline__ float ld_dev_f32(const float* p) {
    return __hip_atomic_load(const_cast<float*>(p), __ATOMIC_RELAXED, __HIP_MEMORY_SCOPE_AGENT);
}
__device__ __forceinline__ void st_dev_f32x2(float* p, float x, float y) {
    union { float2 f; uint64 q; } u; u.f = make_float2(x, y);
    __hip_atomic_store(reinterpret_cast<uint64*>(p), u.q, __ATOMIC_RELAXED, __HIP_MEMORY_SCOPE_AGENT);
}
__device__ __forceinline__ float2 ld_dev_f32x2(const float* p) {
    union { float2 f; uint64 q; } u;
    u.q = __hip_atomic_load(reinterpret_cast<uint64*>(const_cast<float*>(p)),
                            __ATOMIC_RELAXED, __HIP_MEMORY_SCOPE_AGENT);
    return u.f;
}

// ---- cross-lane: sum of the two 32-lane halves, in every lane (VALU, off the DS pipe) ----
__device__ __forceinline__ float halfpair_sum(float x) {
#if __has_builtin(__builtin_amdgcn_permlane32_swap)
    int xi = __float_as_int(x);
    auto sw = __builtin_amdgcn_permlane32_swap(xi, xi, false, false);
    return __int_as_float(sw[0]) + __int_as_float(sw[1]);
#else
    return x + __shfl_xor(x, 32, 64);
#endif
}

// ======================= two-level grid barrier (fence-free, 1-hop wake) =======================
// ctrl dwords: [0]=root_cnt, [128+g*64]=group_cnt, [768+g*64]=group_gen.
// Cross-block DATA moves via agent-scope atomics or write-once cached buffers,
// so no __threadfence (no L2 writeback/invalidate) is needed.
__device__ __forceinline__ void grid_barrier(uint32* ctrl, uint32 rnd) {
    asm volatile("s_waitcnt vmcnt(0)" ::: "memory");   // my stores are at the coherence point
    __syncthreads();
    if (threadIdx.x == 0) {
        const int gid = (int)(blockIdx.x >> 5);
        uint32* gcnt = ctrl + 128 + gid * 64;
        uint32* ggen = ctrl + 768 + gid * 64;
        uint32 a = __hip_atomic_fetch_add(gcnt, 1u, __ATOMIC_RELAXED, __HIP_MEMORY_SCOPE_AGENT);
        if (a == rnd * 32u + 31u) {
            uint32 r = __hip_atomic_fetch_add(ctrl, 1u, __ATOMIC_RELAXED, __HIP_MEMORY_SCOPE_AGENT);
            if (r == rnd * 8u + 7u) {
#pragma unroll
                for (int g = 0; g < 8; ++g)
                    __hip_atomic_store(ctrl + 768 + g * 64, rnd + 1u,
                                       __ATOMIC_RELAXED, __HIP_MEMORY_SCOPE_AGENT);
            }
        }
        while (__hip_atomic_load(ggen, __ATOMIC_RELAXED, __HIP_MEMORY_SCOPE_AGENT) < rnd + 1u)
            __builtin_amdgcn_s_sleep(1);
    }
    __syncthreads();
}

// ======================= init (ws is poisoned before every launch) =======================
__global__ __launch_bounds__(256) void init_kernel(float* __restrict__ u_rot,
                                                   uint32* __restrict__ ctrl,
                                                   float* __restrict__ err2,
                                                   float* __restrict__ loss) {
    int idx = blockIdx.x * 256 + threadIdx.x;
    if (idx < 1280) ctrl[idx] = 0u;
    if (idx == 0) { err2[0] = 0.f; err2[1] = 0.f; *loss = 0.f; }
    if (idx < 2048) u_rot[idx] = (idx < ROWS_R) ? A_MARG : 0.0f;   // zero pad rows!
}

// ======================= LDS-resident-K Sinkhorn, rotating cached u, owner-major P ==========
// Block b owns columns [80b, 80b+80). K stripe in LDS (fp8, col-major, 2004 B stride).
// u(t): rotating write-once slots, plain cached reads (one LLC fill per XCD).
// P2 layout is OWNER-major: P2[c*2048 + b*8 + k] holds block b's partial for row
// 8c+k -> the u-finalize read is one contiguous coalesced 8 KB slice per owner.
__global__ __launch_bounds__(NTHR, 1) void sinkhorn_lds(
    const float* __restrict__ M,
    float* __restrict__ u_rot,        // USLOTS x 2048 floats (pad rows = 0)
    float* __restrict__ P2,           // 256 owners x 2048 floats
    uint32* __restrict__ ctrl,
    float* __restrict__ err2,
    float* __restrict__ loss,
    float* __restrict__ out) {
    __shared__ uint32 sK[KDW + KGUARD];   // ~160.4 KB
    __shared__ float  s_vloc[CPB];
    __shared__ float  s_vprev[CPB];
    __shared__ float  s_red[NWAVE * 8];
    __shared__ int    s_flag;

    const int tid  = threadIdx.x;
    const int lane = tid & 63;
    const int wav  = tid >> 6;
    const int b    = blockIdx.x;
    const int j0   = b * CPB;
    uint32 bar = 0;

    // ---------------- build: zero LDS, then pack exp(-20 M) fp8 col-major ----------------
    for (int i = tid; i < KDW + KGUARD; i += NTHR) sK[i] = 0u;
    __syncthreads();
    for (int q = wav; q < 500; q += NWAVE) {          // row-quad q -> rows 4q..4q+3
#pragma unroll
        for (int ph = 0; ph < 2; ++ph) {
            const int cl = ph * 64 + lane;            // local col 0..79
            const int j  = j0 + cl;
            if ((ph == 0 || lane < 16) && j < COLS_R) {
                const float* mp = M + (size_t)(4 * q) * COLS_R + j;
                float k0 = __expf(NALPHA * mp[0]);
                float k1 = __expf(NALPHA * mp[COLS_R]);
                float k2 = __expf(NALPHA * mp[2 * COLS_R]);
                float k3 = __expf(NALPHA * mp[3 * COLS_R]);
                int lo = __builtin_amdgcn_cvt_pk_fp8_f32(k0, k1, 0, false);
                int hi = __builtin_amdgcn_cvt_pk_fp8_f32(k2, k3, lo, true);
                sK[cl * CSTR + q] = (uint32)hi;       // dword = rows 4q..4q+3 of col cl
            }
        }
    }
    __syncthreads();

    // ---------------- Sinkhorn loop ----------------
    int usel = 0;   // current u slot (u(t-1) at top of iteration t)

    for (int t = 1; t <= 100; ++t) {
        // err check folded: iter t's col pass computes K^T u_{t-1} (= err input at cpt=t-1)
        const bool chk  = (t == 2) || (t == 52);
        const int  slot = (t == 52) ? 1 : 0;

        // preload u(t-1): PLAIN cached float4 loads from write-once slot (L2-shared per XCD)
        const float4* u4 = reinterpret_cast<const float4*>(u_rot + (size_t)usel * 2048);
        float4 u_r[8];
#pragma unroll
        for (int s = 0; s < 8; ++s) u_r[s] = u4[s * 64 + lane];

        // col pass: wave handles 5 of the 80 local columns
        float e = 0.f;
#pragma unroll
        for (int q = 0; q < 5; ++q) {
            const int jl = wav * 5 + q;
            float acc = 0.f;
#pragma unroll
            for (int s = 0; s < 8; ++s) {             // d up to 511: pad/guard are zero, u pad = 0
                uint32 kw = sK[jl * CSTR + s * 64 + lane];
                floatx2 f01 = __builtin_amdgcn_cvt_pk_f32_fp8(kw, false);
                floatx2 f23 = __builtin_amdgcn_cvt_pk_f32_fp8(kw, true);
                acc += f01.x * u_r[s].x + f01.y * u_r[s].y + f23.x * u_r[s].z + f23.y * u_r[s].w;
            }
            acc = halfpair_sum(acc);                  // 64 -> 32 on the VALU pipe
#pragma unroll
            for (int o = 16; o; o >>= 1) acc += __shfl_xor(acc, o, 64);
            if (lane == 0) {
                float vnew = B_MARG / (acc + EPSV);
                if (chk) {
                    float vold = s_vloc[jl];
                    s_vprev[jl] = vold;               // preserve v_{t-1} for break/loss
                    if (j0 + jl < COLS_R) e += fabsf(vold * acc - B_MARG);
                }
                s_vloc[jl] = vnew;
            }
        }
        if (chk && lane == 0) s_red[wav] = e;
        __syncthreads();                              // v_local ready

        // row pass: lane reads 2 consecutive quads (8 rows) of col cl = jp*4 + (lane>>4)
        // (pair merges to ds_read2_b32; CSTR odd so 4-way bank access = data floor).
        // Lane (rg=lane>>4, rm=lane&15) accumulates rows wav*128 + 8*rm .. +7 over
        // 20 of the 80 cols; xor16 + halfpair then sums the 4 col-subgroups.
        {
            const int rg = lane >> 4;                 // column subgroup 0..3
            const int rm = lane & 15;                 // row-octet index
            const int qb = wav * 32 + 2 * rm;         // first of 2 consecutive quads
            float4 pb0 = make_float4(0.f, 0.f, 0.f, 0.f);
            float4 pb1 = make_float4(0.f, 0.f, 0.f, 0.f);
#pragma unroll 5
            for (int jp = 0; jp < 20; ++jp) {
                const int cl = jp * 4 + rg;
                uint32 ka = sK[cl * CSTR + qb];       // rows 8rm..8rm+3 (of wave's 128)
                uint32 kb = sK[cl * CSTR + qb + 1];   // rows 8rm+4..8rm+7
                float  vv = s_vloc[cl];
                floatx2 a01 = __builtin_amdgcn_cvt_pk_f32_fp8(ka, false);
                floatx2 a23 = __builtin_amdgcn_cvt_pk_f32_fp8(ka, true);
                floatx2 b01 = __builtin_amdgcn_cvt_pk_f32_fp8(kb, false);
                floatx2 b23 = __builtin_amdgcn_cvt_pk_f32_fp8(kb, true);
                pb0.x += a01.x * vv; pb0.y += a01.y * vv;
                pb0.z += a23.x * vv; pb0.w += a23.y * vv;
                pb1.x += b01.x * vv; pb1.y += b01.y * vv;
                pb1.z += b23.x * vv; pb1.w += b23.y * vv;
            }
            // combine the 4 column subgroups (lanes rg*16+rm): xor16 then 32-swap
            pb0.x += __shfl_xor(pb0.x, 16, 64);  pb0.y += __shfl_xor(pb0.y, 16, 64);
            pb0.z += __shfl_xor(pb0.z, 16, 64);  pb0.w += __shfl_xor(pb0.w, 16, 64);
            pb1.x += __shfl_xor(pb1.x, 16, 64);  pb1.y += __shfl_xor(pb1.y, 16, 64);
            pb1.z += __shfl_xor(pb1.z, 16, 64);  pb1.w += __shfl_xor(pb1.w, 16, 64);
            pb0.x = halfpair_sum(pb0.x);  pb0.y = halfpair_sum(pb0.y);
            pb0.z = halfpair_sum(pb0.z);  pb0.w = halfpair_sum(pb0.w);
            pb1.x = halfpair_sum(pb1.x);  pb1.y = halfpair_sum(pb1.y);
            pb1.z = halfpair_sum(pb1.z);  pb1.w = halfpair_sum(pb1.w);
            if (lane < 16) {                          // owner c = wav*16 + rm; 8 floats, 32 B
                float* dst = P2 + (size_t)(wav * 16 + lane) * 2048 + b * 8;
                st_dev_f32x2(dst,     pb0.x, pb0.y);
                st_dev_f32x2(dst + 2, pb0.z, pb0.w);
                st_dev_f32x2(dst + 4, pb1.x, pb1.y);
                st_dev_f32x2(dst + 6, pb1.z, pb1.w);
            }
        }

        if (chk && tid == 0) {
            float s = 0.f;
            for (int k = 0; k < NWAVE; ++k) s += s_red[k];
            if (s != 0.f) atomicAdd(&err2[slot], s);
        }
        grid_barrier(ctrl, bar++);

        if (chk) {
            if (tid == 0) s_flag = (ld_dev_f32(&err2[slot]) <= THR) ? 1 : 0;
            __syncthreads();
            if (s_flag) {                             // converged at cpt=t-1
                if (tid < CPB) s_vloc[tid] = s_vprev[tid];   // restore v_{t-1} for loss
                __syncthreads();
                break;                                // usel still = t-1 slot
            }
        }

        // finalize u: owner b reads its CONTIGUOUS 8 KB slice of P2 (coalesced agent
        // loads, 2 lines/wave), reduces 256 partials per row, writes u(t) to slot t.
        {
            float2 pr = ld_dev_f32x2(P2 + (size_t)b * 2048 + tid * 2);
            // element j = 2*tid: source block b' = tid>>2, k-pair = lane&3 (k=2*(lane&3),+1)
            // butterfly over b' within wave: lanes stride 4
            pr.x += __shfl_xor(pr.x, 4, 64);   pr.y += __shfl_xor(pr.y, 4, 64);
            pr.x += __shfl_xor(pr.x, 8, 64);   pr.y += __shfl_xor(pr.y, 8, 64);
            pr.x += __shfl_xor(pr.x, 16, 64);  pr.y += __shfl_xor(pr.y, 16, 64);
            pr.x = halfpair_sum(pr.x);         pr.y = halfpair_sum(pr.y);
            if (lane < 4) {                           // wave-partial for k = 2*lane, 2*lane+1
                s_red[wav * 8 + 2 * lane]     = pr.x;
                s_red[wav * 8 + 2 * lane + 1] = pr.y;
            }
        }
        __syncthreads();
        if (tid < 8) {
            float s = 0.f;
            for (int w = 0; w < NWAVE; ++w) s += s_red[w * 8 + tid];
            const int row = 8 * b + tid;
            float val = (row < ROWS_R) ? A_MARG / (s + EPSV) : 0.0f;  // keep pad zero!
            st_dev_f32(u_rot + (size_t)t * 2048 + row, val);
        }
        usel = t;
        grid_barrier(ctrl, bar++);
    }

    // ---------------- loss = sum_ij u_i exp(-20 M_ij) v_j M_ij (fp32 from M) ----------------
    {
        const float* uf = u_rot + (size_t)usel * 2048;   // final u slot (cached reads safe)
        float acc = 0.f;
        for (int r = wav; r < ROWS_R; r += NWAVE) {
            const float uu = uf[r];                   // wave-uniform scalar
            const float* mp = M + (size_t)r * COLS_R + j0;
#pragma unroll
            for (int ph = 0; ph < 2; ++ph) {
                const int cl = ph * 64 + lane;
                if ((ph == 0 || lane < 16) && (j0 + cl) < COLS_R) {
                    float m = mp[cl];
                    acc += uu * __expf(NALPHA * m) * s_vloc[cl] * m;
                }
            }
        }
        acc = halfpair_sum(acc);
#pragma unroll
        for (int o = 16; o; o >>= 1) acc += __shfl_xor(acc, o, 64);
        if (lane == 0) s_red[wav] = acc;
        __syncthreads();
        if (tid == 0) {
            float s = 0.f;
            for (int k = 0; k < NWAVE; ++k) s += s_red[k];
            if (s != 0.f) atomicAdd(loss, s);
        }
    }
    grid_barrier(ctrl, bar++);
    if (b == 0 && tid == 0) out[0] = ld_dev_f32(loss) * 100.0f;
}

// ======================= fallback path (tiny workspace) =======================

__device__ __forceinline__ float block_reduce_sum256(float v) {
#pragma unroll
    for (int o = 32; o; o >>= 1) v += __shfl_down(v, o, 64);
    __shared__ float smem[4];
    int lane = threadIdx.x & 63, w = threadIdx.x >> 6;
    if (lane == 0) smem[w] = v;
    __syncthreads();
    v = (threadIdx.x < 4) ? smem[threadIdx.x] : 0.0f;
    v += __shfl_down(v, 2, 64);
    v += __shfl_down(v, 1, 64);
    return v;
}

__global__ __launch_bounds__(256) void fb_init(float* u, float* vden, int* done, float* err, float* loss) {
    int idx = blockIdx.x * 256 + threadIdx.x;
    if (idx == 0) { *done = 0; *err = 0.0f; *loss = 0.0f; }
    if (idx < ROWS_R) u[idx] = A_MARG;
    if (idx < COLS_R) vden[idx] = 0.0f;
}
__global__ __launch_bounds__(256) void fb_colpass(const float* __restrict__ M, const float* __restrict__ u,
                                                  float* __restrict__ vden, const int* __restrict__ done) {
    if (*done) return;
    int c4 = blockIdx.x * 256 + threadIdx.x;
    if (c4 >= 5000) return;
    int r0 = blockIdx.y * 50;
    float4 acc = make_float4(0.f, 0.f, 0.f, 0.f);
    for (int r = r0; r < r0 + 50; ++r) {
        float ui = u[r];
        float4 mm = reinterpret_cast<const float4*>(M)[(size_t)r * 5000 + c4];
        acc.x += __expf(NALPHA * mm.x) * ui; acc.y += __expf(NALPHA * mm.y) * ui;
        acc.z += __expf(NALPHA * mm.z) * ui; acc.w += __expf(NALPHA * mm.w) * ui;
    }
    atomicAdd(&vden[c4 * 4 + 0], acc.x); atomicAdd(&vden[c4 * 4 + 1], acc.y);
    atomicAdd(&vden[c4 * 4 + 2], acc.z); atomicAdd(&vden[c4 * 4 + 3], acc.w);
}
__global__ __launch_bounds__(256) void fb_finv(float* v, float* vden, const int* done) {
    if (*done) return;
    int j = blockIdx.x * 256 + threadIdx.x;
    if (j < COLS_R) { v[j] = B_MARG / (vden[j] + EPSV); vden[j] = 0.0f; }
}
__global__ __launch_bounds__(256) void fb_rowpass(const float* __restrict__ M, const float* __restrict__ v,
                                                  float* __restrict__ u, const int* __restrict__ done) {
    if (*done) return;
    int row = blockIdx.x;
    const float4* v4 = reinterpret_cast<const float4*>(v);
    float acc = 0.0f;
    for (int c4 = threadIdx.x; c4 < 5000; c4 += 256) {
        float4 mm = reinterpret_cast<const float4*>(M)[(size_t)row * 5000 + c4];
        float4 vv = v4[c4];
        acc += __expf(NALPHA * mm.x) * vv.x + __expf(NALPHA * mm.y) * vv.y
             + __expf(NALPHA * mm.z) * vv.z + __expf(NALPHA * mm.w) * vv.w;
    }
    float s = block_reduce_sum256(acc);
    if (threadIdx.x == 0) u[row] = A_MARG / (s + EPSV);
}
__global__ __launch_bounds__(256) void fb_errfin(const float* v, float* vden, float* err, const int* done) {
    if (*done) return;
    int j = blockIdx.x * 256 + threadIdx.x;
    float local = 0.0f;
    if (j < COLS_R) { local = fabsf(v[j] * vden[j] - B_MARG); vden[j] = 0.0f; }
    float s = block_reduce_sum256(local);
    if (threadIdx.x == 0) atomicAdd(err, s);
}
__global__ void fb_check(int* done, float* err) {
    if (threadIdx.x == 0) { if (!*done && *err <= THR) *done = 1; *err = 0.0f; }
}
__global__ __launch_bounds__(256) void fb_loss(const float* __restrict__ M, const float* __restrict__ u,
                                               const float* __restrict__ v, float* __restrict__ loss) {
    int row = blockIdx.x;
    const float4* M4p = reinterpret_cast<const float4*>(M + (size_t)row * COLS_R);
    const float4* v4 = reinterpret_cast<const float4*>(v);
    float acc = 0.0f;
    for (int c4 = threadIdx.x; c4 < 5000; c4 += 256) {
        float4 mm = M4p[c4]; float4 vv = v4[c4];
        acc += __expf(NALPHA * mm.x) * vv.x * mm.x + __expf(NALPHA * mm.y) * vv.y * mm.y
             + __expf(NALPHA * mm.z) * vv.z * mm.z + __expf(NALPHA * mm.w) * vv.w * mm.w;
    }
    float s = block_reduce_sum256(acc);
    if (threadIdx.x == 0) atomicAdd(loss, s * u[row]);
}
__global__ void fb_writeout(float* out, const float* loss) {
    if (threadIdx.x == 0) out[0] = *loss * 100.0f;
}

// ======================= host launch =======================

extern "C" void kernel_launch(void* const* d_in, const int* in_sizes, int n_in,
                              void* d_out, int out_size, void* d_ws, size_t ws_size,
                              hipStream_t stream) {
    const float* M = (const float*)d_in[0];
    char* base = (char*)d_ws;

    const size_t OFF_CTRL = 0;                        // uint32[2048] (8 KB; 1280 used)
    const size_t OFF_ERR  = 8192;
    const size_t OFF_LOSS = 8320;
    const size_t OFF_UROT = 8448;                     // USLOTS x 2048 floats (16B aligned)
    const size_t OFF_P    = OFF_UROT + (size_t)USLOTS * 2048 * 4;   // 256 x 2048 floats
    const size_t NEED     = OFF_P + (size_t)NBLK * 2048 * 4;        // ~2.93 MB

    if (ws_size >= NEED) {
        uint32* ctrl  = (uint32*)(base + OFF_CTRL);
        float*  err2  = (float*)(base + OFF_ERR);
        float*  loss  = (float*)(base + OFF_LOSS);
        float*  u_rot = (float*)(base + OFF_UROT);
        float*  P2    = (float*)(base + OFF_P);

        init_kernel<<<8, 256, 0, stream>>>(u_rot, ctrl, err2, loss);
        sinkhorn_lds<<<NBLK, NTHR, 0, stream>>>(M, u_rot, P2, ctrl, err2, loss, (float*)d_out);
    } else {
        int*   done = (int*)(base + 0);
        float* err  = (float*)(base + 8);
        float* loss = (float*)(base + 16);
        float* u    = (float*)(base + 64);
        float* v    = (float*)(base + 64 + 8192);
        float* vden = (float*)(base + 64 + 8192 + 80000);

        fb_init<<<79, 256, 0, stream>>>(u, vden, done, err, loss);
        dim3 cgrid(20, 40);
        for (int t = 1; t <= 100; ++t) {
            fb_colpass<<<cgrid, 256, 0, stream>>>(M, u, vden, done);
            fb_finv<<<79, 256, 0, stream>>>(v, vden, done);
            fb_rowpass<<<ROWS_R, 256, 0, stream>>>(M, v, u, done);
            if (t == 1 || t == 51) {
                fb_colpass<<<cgrid, 256, 0, stream>>>(M, u, vden, done);
                fb_errfin<<<79, 256, 0, stream>>>(v, vden, err, done);
                fb_check<<<1, 64, 0, stream>>>(done, err);
            }
        }
        fb_loss<<<ROWS_R, 256, 0, stream>>>(M, u, v, loss);
        fb_writeout<<<1, 64, 0, stream>>>((float*)d_out, loss);
    }
}

// Round 9
// 333.754 us; speedup vs baseline: 1.0041x; 1.0041x over previous
//
#include <hip/hip_runtime.h>

typedef unsigned int uint32;
typedef unsigned long long uint64;
typedef float floatx2 __attribute__((ext_vector_type(2)));

#define ROWS_R 2000
#define COLS_R 20000
#define NBLK   256
#define NTHR   1024
#define NWAVE  16
#define CPB    80          /* columns per block: 250 blocks cover 20000; 250..255 all-pad */
#define CSTR   501         /* LDS column stride in dwords (2004 B): 500 data + 1 zero pad */
#define KDW    (CPB*CSTR)  /* 40080 dwords = 160320 B */
#define KGUARD 16          /* zero guard so col-pass tail reads (d<=511) stay in-bounds */
#define USLOTS 101         /* rotating u buffers: slot t = u(t); never re-read a stale line */

static constexpr float A_MARG = 1.0f / 2000.0f;
static constexpr float B_MARG = 1.0f / 20000.0f;
static constexpr float EPSV   = 1e-16f;
static constexpr float THR    = 0.005f;
static constexpr float NALPHA = -20.0f;

// ---- agent-scope (device-coherent) access helpers: bypass the non-coherent L2 ----
__device__ __forceinline__ void st_dev_f32(float* p, float v) {
    __hip_atomic_store(p, v, __ATOMIC_RELAXED, __HIP_MEMORY_SCOPE_AGENT);
}
__device__ __forceinline__ float ld_dev_f32(const float* p) {
    return __hip_atomic_load(const_cast<float*>(p), __ATOMIC_RELAXED, __HIP_MEMORY_SCOPE_AGENT);
}
__device__ __forceinline__ void st_dev_f32x2(float* p, float x, float y) {
    union { float2 f; uint64 q; } u; u.f = make_float2(x, y);
    __hip_atomic_store(reinterpret_cast<uint64*>(p), u.q, __ATOMIC_RELAXED, __HIP_MEMORY_SCOPE_AGENT);
}
__device__ __forceinline__ float2 ld_dev_f32x2(const float* p) {
    union { float2 f; uint64 q; } u;
    u.q = __hip_atomic_load(reinterpret_cast<uint64*>(const_cast<float*>(p)),
                            __ATOMIC_RELAXED, __HIP_MEMORY_SCOPE_AGENT);
    return u.f;
}

// ==================== VALU-resident cross-lane reductions (zero DS-pipe ops) ====================
// The K-stripe sweeps saturate the DS port; every shuffle moved to VALU is a DS
// cycle returned to the sweeps. Rotation ladders are valid for sum-reductions
// (after ror8,ror4,ror2,ror1 every lane holds the full 16-row sum).

// x[l] + x[l^32], in every lane (VALU v_permlane32_swap)
__device__ __forceinline__ float halfpair_sum(float x) {
#if __has_builtin(__builtin_amdgcn_permlane32_swap)
    int xi = __float_as_int(x);
    auto sw = __builtin_amdgcn_permlane32_swap(xi, xi, false, false);
    return __int_as_float(sw[0]) + __int_as_float(sw[1]);
#else
    return x + __shfl_xor(x, 32, 64);
#endif
}

// x[l] + x[l^16], in every lane (VALU v_permlane16_swap)
__device__ __forceinline__ float pair16_sum(float x) {
#if __has_builtin(__builtin_amdgcn_permlane16_swap)
    int xi = __float_as_int(x);
    auto sw = __builtin_amdgcn_permlane16_swap(xi, xi, false, false);
    return __int_as_float(sw[0]) + __int_as_float(sw[1]);
#else
    return x + __shfl_xor(x, 16, 64);
#endif
}

// x + row_ror<N>(x) via DPP (VALU). ctrl: ror1=0x121 ror2=0x122 ror4=0x124 ror8=0x128
template <int CTRL>
__device__ __forceinline__ float dpp_ror_add(float x) {
#if __has_builtin(__builtin_amdgcn_update_dpp)
    int xi = __float_as_int(x);
    int sh = __builtin_amdgcn_update_dpp(0, xi, CTRL, 0xF, 0xF, true);
    return x + __int_as_float(sh);
#else
    // fallback: equivalent-sum xor shuffles
    const int off = (CTRL == 0x128) ? 8 : (CTRL == 0x124) ? 4 : (CTRL == 0x122) ? 2 : 1;
    return x + __shfl_xor(x, off, 64);
#endif
}

// full sum within each 16-lane row, result in every lane (4 VALU DPP adds)
__device__ __forceinline__ float rowsum16(float x) {
    x = dpp_ror_add<0x128>(x);
    x = dpp_ror_add<0x124>(x);
    x = dpp_ror_add<0x122>(x);
    x = dpp_ror_add<0x121>(x);
    return x;
}

// ======================= two-level grid barrier (fence-free, 1-hop wake) =======================
__device__ __forceinline__ void grid_barrier(uint32* ctrl, uint32 rnd) {
    asm volatile("s_waitcnt vmcnt(0)" ::: "memory");   // my stores are at the coherence point
    __syncthreads();
    if (threadIdx.x == 0) {
        const int gid = (int)(blockIdx.x >> 5);
        uint32* gcnt = ctrl + 128 + gid * 64;
        uint32* ggen = ctrl + 768 + gid * 64;
        uint32 a = __hip_atomic_fetch_add(gcnt, 1u, __ATOMIC_RELAXED, __HIP_MEMORY_SCOPE_AGENT);
        if (a == rnd * 32u + 31u) {
            uint32 r = __hip_atomic_fetch_add(ctrl, 1u, __ATOMIC_RELAXED, __HIP_MEMORY_SCOPE_AGENT);
            if (r == rnd * 8u + 7u) {
#pragma unroll
                for (int g = 0; g < 8; ++g)
                    __hip_atomic_store(ctrl + 768 + g * 64, rnd + 1u,
                                       __ATOMIC_RELAXED, __HIP_MEMORY_SCOPE_AGENT);
            }
        }
        while (__hip_atomic_load(ggen, __ATOMIC_RELAXED, __HIP_MEMORY_SCOPE_AGENT) < rnd + 1u)
            __builtin_amdgcn_s_sleep(1);
    }
    __syncthreads();
}

// ======================= init (ws is poisoned before every launch) =======================
__global__ __launch_bounds__(256) void init_kernel(float* __restrict__ u_rot,
                                                   uint32* __restrict__ ctrl,
                                                   float* __restrict__ err2,
                                                   float* __restrict__ loss) {
    int idx = blockIdx.x * 256 + threadIdx.x;
    if (idx < 1280) ctrl[idx] = 0u;
    if (idx == 0) { err2[0] = 0.f; err2[1] = 0.f; *loss = 0.f; }
    if (idx < 2048) u_rot[idx] = (idx < ROWS_R) ? A_MARG : 0.0f;   // zero pad rows!
}

// ======================= LDS-resident-K Sinkhorn, rotating cached u, owner-major P ==========
__global__ __launch_bounds__(NTHR, 1) void sinkhorn_lds(
    const float* __restrict__ M,
    float* __restrict__ u_rot,        // USLOTS x 2048 floats (pad rows = 0)
    float* __restrict__ P2,           // 256 owners x 2048 floats
    uint32* __restrict__ ctrl,
    float* __restrict__ err2,
    float* __restrict__ loss,
    float* __restrict__ out) {
    __shared__ uint32 sK[KDW + KGUARD];   // ~160.4 KB
    __shared__ float  s_vloc[CPB];
    __shared__ float  s_vprev[CPB];
    __shared__ float  s_red[NWAVE * 8];
    __shared__ int    s_flag;

    const int tid  = threadIdx.x;
    const int lane = tid & 63;
    const int wav  = tid >> 6;
    const int b    = blockIdx.x;
    const int j0   = b * CPB;
    uint32 bar = 0;

    // ---------------- build: zero LDS, then pack exp(-20 M) fp8 col-major ----------------
    for (int i = tid; i < KDW + KGUARD; i += NTHR) sK[i] = 0u;
    __syncthreads();
    for (int q = wav; q < 500; q += NWAVE) {          // row-quad q -> rows 4q..4q+3
#pragma unroll
        for (int ph = 0; ph < 2; ++ph) {
            const int cl = ph * 64 + lane;            // local col 0..79
            const int j  = j0 + cl;
            if ((ph == 0 || lane < 16) && j < COLS_R) {
                const float* mp = M + (size_t)(4 * q) * COLS_R + j;
                float k0 = __expf(NALPHA * mp[0]);
                float k1 = __expf(NALPHA * mp[COLS_R]);
                float k2 = __expf(NALPHA * mp[2 * COLS_R]);
                float k3 = __expf(NALPHA * mp[3 * COLS_R]);
                int lo = __builtin_amdgcn_cvt_pk_fp8_f32(k0, k1, 0, false);
                int hi = __builtin_amdgcn_cvt_pk_fp8_f32(k2, k3, lo, true);
                sK[cl * CSTR + q] = (uint32)hi;       // dword = rows 4q..4q+3 of col cl
            }
        }
    }
    __syncthreads();

    // ---------------- Sinkhorn loop ----------------
    int usel = 0;   // current u slot (u(t-1) at top of iteration t)

    for (int t = 1; t <= 100; ++t) {
        // err check folded: iter t's col pass computes K^T u_{t-1} (= err input at cpt=t-1)
        const bool chk  = (t == 2) || (t == 52);
        const int  slot = (t == 52) ? 1 : 0;

        // preload u(t-1): PLAIN cached float4 loads from write-once slot (L2-shared per XCD)
        const float4* u4 = reinterpret_cast<const float4*>(u_rot + (size_t)usel * 2048);
        float4 u_r[8];
#pragma unroll
        for (int s = 0; s < 8; ++s) u_r[s] = u4[s * 64 + lane];

        // col pass: wave handles 5 of the 80 local columns; reduction fully on VALU
        float e = 0.f;
#pragma unroll
        for (int q = 0; q < 5; ++q) {
            const int jl = wav * 5 + q;
            float acc = 0.f;
#pragma unroll
            for (int s = 0; s < 8; ++s) {             // d up to 511: pad/guard are zero, u pad = 0
                uint32 kw = sK[jl * CSTR + s * 64 + lane];
                floatx2 f01 = __builtin_amdgcn_cvt_pk_f32_fp8(kw, false);
                floatx2 f23 = __builtin_amdgcn_cvt_pk_f32_fp8(kw, true);
                acc += f01.x * u_r[s].x + f01.y * u_r[s].y + f23.x * u_r[s].z + f23.y * u_r[s].w;
            }
            acc = halfpair_sum(acc);                  // +x[l^32]  (VALU)
            acc = pair16_sum(acc);                    // +x[l^16]  (VALU)
            acc = rowsum16(acc);                      // sum 16-row (VALU DPP)
            if (lane == 0) {
                float vnew = B_MARG / (acc + EPSV);
                if (chk) {
                    float vold = s_vloc[jl];
                    s_vprev[jl] = vold;               // preserve v_{t-1} for break/loss
                    if (j0 + jl < COLS_R) e += fabsf(vold * acc - B_MARG);
                }
                s_vloc[jl] = vnew;
            }
        }
        if (chk && lane == 0) s_red[wav] = e;
        __syncthreads();                              // v_local ready

        // row pass: lane reads 2 consecutive quads (8 rows) of col cl = jp*4 + (lane>>4);
        // subgroup combine on VALU (pair16 + halfpair)
        {
            const int rg = lane >> 4;                 // column subgroup 0..3
            const int rm = lane & 15;                 // row-octet index
            const int qb = wav * 32 + 2 * rm;         // first of 2 consecutive quads
            float4 pb0 = make_float4(0.f, 0.f, 0.f, 0.f);
            float4 pb1 = make_float4(0.f, 0.f, 0.f, 0.f);
#pragma unroll 5
            for (int jp = 0; jp < 20; ++jp) {
                const int cl = jp * 4 + rg;
                uint32 ka = sK[cl * CSTR + qb];       // rows 8rm..8rm+3 (of wave's 128)
                uint32 kb = sK[cl * CSTR + qb + 1];   // rows 8rm+4..8rm+7
                float  vv = s_vloc[cl];
                floatx2 a01 = __builtin_amdgcn_cvt_pk_f32_fp8(ka, false);
                floatx2 a23 = __builtin_amdgcn_cvt_pk_f32_fp8(ka, true);
                floatx2 b01 = __builtin_amdgcn_cvt_pk_f32_fp8(kb, false);
                floatx2 b23 = __builtin_amdgcn_cvt_pk_f32_fp8(kb, true);
                pb0.x += a01.x * vv; pb0.y += a01.y * vv;
                pb0.z += a23.x * vv; pb0.w += a23.y * vv;
                pb1.x += b01.x * vv; pb1.y += b01.y * vv;
                pb1.z += b23.x * vv; pb1.w += b23.y * vv;
            }
            pb0.x = pair16_sum(pb0.x);  pb0.y = pair16_sum(pb0.y);
            pb0.z = pair16_sum(pb0.z);  pb0.w = pair16_sum(pb0.w);
            pb1.x = pair16_sum(pb1.x);  pb1.y = pair16_sum(pb1.y);
            pb1.z = pair16_sum(pb1.z);  pb1.w = pair16_sum(pb1.w);
            pb0.x = halfpair_sum(pb0.x);  pb0.y = halfpair_sum(pb0.y);
            pb0.z = halfpair_sum(pb0.z);  pb0.w = halfpair_sum(pb0.w);
            pb1.x = halfpair_sum(pb1.x);  pb1.y = halfpair_sum(pb1.y);
            pb1.z = halfpair_sum(pb1.z);  pb1.w = halfpair_sum(pb1.w);
            if (lane < 16) {                          // owner c = wav*16 + lane; 8 floats, 32 B
                float* dst = P2 + (size_t)(wav * 16 + lane) * 2048 + b * 8;
                st_dev_f32x2(dst,     pb0.x, pb0.y);
                st_dev_f32x2(dst + 2, pb0.z, pb0.w);
                st_dev_f32x2(dst + 4, pb1.x, pb1.y);
                st_dev_f32x2(dst + 6, pb1.z, pb1.w);
            }
        }

        if (chk && tid == 0) {
            float s = 0.f;
            for (int k = 0; k < NWAVE; ++k) s += s_red[k];
            if (s != 0.f) atomicAdd(&err2[slot], s);
        }
        grid_barrier(ctrl, bar++);

        if (chk) {
            if (tid == 0) s_flag = (ld_dev_f32(&err2[slot]) <= THR) ? 1 : 0;
            __syncthreads();
            if (s_flag) {                             // converged at cpt=t-1
                if (tid < CPB) s_vloc[tid] = s_vprev[tid];   // restore v_{t-1} for loss
                __syncthreads();
                break;                                // usel still = t-1 slot
            }
        }

        // finalize u: owner b reads its CONTIGUOUS 8 KB slice of P2 (coalesced agent
        // loads), reduces 256 partials per row on the VALU, writes u(t) to slot t.
        {
            float2 pr = ld_dev_f32x2(P2 + (size_t)b * 2048 + tid * 2);
            // reduce over source blocks (lanes stride 4): ror4+ror8 (class l&3 preserved),
            // then 16- and 32-offset pair sums — all VALU
            pr.x = dpp_ror_add<0x124>(pr.x);  pr.y = dpp_ror_add<0x124>(pr.y);
            pr.x = dpp_ror_add<0x128>(pr.x);  pr.y = dpp_ror_add<0x128>(pr.y);
            pr.x = pair16_sum(pr.x);          pr.y = pair16_sum(pr.y);
            pr.x = halfpair_sum(pr.x);        pr.y = halfpair_sum(pr.y);
            if (lane < 4) {                           // wave-partial for k = 2*lane, 2*lane+1
                s_red[wav * 8 + 2 * lane]     = pr.x;
                s_red[wav * 8 + 2 * lane + 1] = pr.y;
            }
        }
        __syncthreads();
        if (tid < 8) {
            float s = 0.f;
            for (int w = 0; w < NWAVE; ++w) s += s_red[w * 8 + tid];
            const int row = 8 * b + tid;
            float val = (row < ROWS_R) ? A_MARG / (s + EPSV) : 0.0f;  // keep pad zero!
            st_dev_f32(u_rot + (size_t)t * 2048 + row, val);
        }
        usel = t;
        grid_barrier(ctrl, bar++);
    }

    // ---------------- loss = sum_ij u_i exp(-20 M_ij) v_j M_ij (fp32 from M) ----------------
    {
        const float* uf = u_rot + (size_t)usel * 2048;   // final u slot (cached reads safe)
        float acc = 0.f;
        for (int r = wav; r < ROWS_R; r += NWAVE) {
            const float uu = uf[r];                   // wave-uniform scalar
            const float* mp = M + (size_t)r * COLS_R + j0;
#pragma unroll
            for (int ph = 0; ph < 2; ++ph) {
                const int cl = ph * 64 + lane;
                if ((ph == 0 || lane < 16) && (j0 + cl) < COLS_R) {
                    float m = mp[cl];
                    acc += uu * __expf(NALPHA * m) * s_vloc[cl] * m;
                }
            }
        }
        acc = halfpair_sum(acc);
        acc = pair16_sum(acc);
        acc = rowsum16(acc);
        if (lane == 0) s_red[wav] = acc;
        __syncthreads();
        if (tid == 0) {
            float s = 0.f;
            for (int k = 0; k < NWAVE; ++k) s += s_red[k];
            if (s != 0.f) atomicAdd(loss, s);
        }
    }
    grid_barrier(ctrl, bar++);
    if (b == 0 && tid == 0) out[0] = ld_dev_f32(loss) * 100.0f;
}

// ======================= fallback path (tiny workspace) =======================

__device__ __forceinline__ float block_reduce_sum256(float v) {
#pragma unroll
    for (int o = 32; o; o >>= 1) v += __shfl_down(v, o, 64);
    __shared__ float smem[4];
    int lane = threadIdx.x & 63, w = threadIdx.x >> 6;
    if (lane == 0) smem[w] = v;
    __syncthreads();
    v = (threadIdx.x < 4) ? smem[threadIdx.x] : 0.0f;
    v += __shfl_down(v, 2, 64);
    v += __shfl_down(v, 1, 64);
    return v;
}

__global__ __launch_bounds__(256) void fb_init(float* u, float* vden, int* done, float* err, float* loss) {
    int idx = blockIdx.x * 256 + threadIdx.x;
    if (idx == 0) { *done = 0; *err = 0.0f; *loss = 0.0f; }
    if (idx < ROWS_R) u[idx] = A_MARG;
    if (idx < COLS_R) vden[idx] = 0.0f;
}
__global__ __launch_bounds__(256) void fb_colpass(const float* __restrict__ M, const float* __restrict__ u,
                                                  float* __restrict__ vden, const int* __restrict__ done) {
    if (*done) return;
    int c4 = blockIdx.x * 256 + threadIdx.x;
    if (c4 >= 5000) return;
    int r0 = blockIdx.y * 50;
    float4 acc = make_float4(0.f, 0.f, 0.f, 0.f);
    for (int r = r0; r < r0 + 50; ++r) {
        float ui = u[r];
        float4 mm = reinterpret_cast<const float4*>(M)[(size_t)r * 5000 + c4];
        acc.x += __expf(NALPHA * mm.x) * ui; acc.y += __expf(NALPHA * mm.y) * ui;
        acc.z += __expf(NALPHA * mm.z) * ui; acc.w += __expf(NALPHA * mm.w) * ui;
    }
    atomicAdd(&vden[c4 * 4 + 0], acc.x); atomicAdd(&vden[c4 * 4 + 1], acc.y);
    atomicAdd(&vden[c4 * 4 + 2], acc.z); atomicAdd(&vden[c4 * 4 + 3], acc.w);
}
__global__ __launch_bounds__(256) void fb_finv(float* v, float* vden, const int* done) {
    if (*done) return;
    int j = blockIdx.x * 256 + threadIdx.x;
    if (j < COLS_R) { v[j] = B_MARG / (vden[j] + EPSV); vden[j] = 0.0f; }
}
__global__ __launch_bounds__(256) void fb_rowpass(const float* __restrict__ M, const float* __restrict__ v,
                                                  float* __restrict__ u, const int* __restrict__ done) {
    if (*done) return;
    int row = blockIdx.x;
    const float4* v4 = reinterpret_cast<const float4*>(v);
    float acc = 0.0f;
    for (int c4 = threadIdx.x; c4 < 5000; c4 += 256) {
        float4 mm = reinterpret_cast<const float4*>(M)[(size_t)row * 5000 + c4];
        float4 vv = v4[c4];
        acc += __expf(NALPHA * mm.x) * vv.x + __expf(NALPHA * mm.y) * vv.y
             + __expf(NALPHA * mm.z) * vv.z + __expf(NALPHA * mm.w) * vv.w;
    }
    float s = block_reduce_sum256(acc);
    if (threadIdx.x == 0) u[row] = A_MARG / (s + EPSV);
}
__global__ __launch_bounds__(256) void fb_errfin(const float* v, float* vden, float* err, const int* done) {
    if (*done) return;
    int j = blockIdx.x * 256 + threadIdx.x;
    float local = 0.0f;
    if (j < COLS_R) { local = fabsf(v[j] * vden[j] - B_MARG); vden[j] = 0.0f; }
    float s = block_reduce_sum256(local);
    if (threadIdx.x == 0) atomicAdd(err, s);
}
__global__ void fb_check(int* done, float* err) {
    if (threadIdx.x == 0) { if (!*done && *err <= THR) *done = 1; *err = 0.0f; }
}
__global__ __launch_bounds__(256) void fb_loss(const float* __restrict__ M, const float* __restrict__ u,
                                               const float* __restrict__ v, float* __restrict__ loss) {
    int row = blockIdx.x;
    const float4* M4p = reinterpret_cast<const float4*>(M + (size_t)row * COLS_R);
    const float4* v4 = reinterpret_cast<const float4*>(v);
    float acc = 0.0f;
    for (int c4 = threadIdx.x; c4 < 5000; c4 += 256) {
        float4 mm = M4p[c4]; float4 vv = v4[c4];
        acc += __expf(NALPHA * mm.x) * vv.x * mm.x + __expf(NALPHA * mm.y) * vv.y * mm.y
             + __expf(NALPHA * mm.z) * vv.z * mm.z + __expf(NALPHA * mm.w) * vv.w * mm.w;
    }
    float s = block_reduce_sum256(acc);
    if (threadIdx.x == 0) atomicAdd(loss, s * u[row]);
}
__global__ void fb_writeout(float* out, const float* loss) {
    if (threadIdx.x == 0) out[0] = *loss * 100.0f;
}

// ======================= host launch =======================

extern "C" void kernel_launch(void* const* d_in, const int* in_sizes, int n_in,
                              void* d_out, int out_size, void* d_ws, size_t ws_size,
                              hipStream_t stream) {
    const float* M = (const float*)d_in[0];
    char* base = (char*)d_ws;

    const size_t OFF_CTRL = 0;                        // uint32[2048] (8 KB; 1280 used)
    const size_t OFF_ERR  = 8192;
    const size_t OFF_LOSS = 8320;
    const size_t OFF_UROT = 8448;                     // USLOTS x 2048 floats (16B aligned)
    const size_t OFF_P    = OFF_UROT + (size_t)USLOTS * 2048 * 4;   // 256 x 2048 floats
    const size_t NEED     = OFF_P + (size_t)NBLK * 2048 * 4;        // ~2.93 MB

    if (ws_size >= NEED) {
        uint32* ctrl  = (uint32*)(base + OFF_CTRL);
        float*  err2  = (float*)(base + OFF_ERR);
        float*  loss  = (float*)(base + OFF_LOSS);
        float*  u_rot = (float*)(base + OFF_UROT);
        float*  P2    = (float*)(base + OFF_P);

        init_kernel<<<8, 256, 0, stream>>>(u_rot, ctrl, err2, loss);
        sinkhorn_lds<<<NBLK, NTHR, 0, stream>>>(M, u_rot, P2, ctrl, err2, loss, (float*)d_out);
    } else {
        int*   done = (int*)(base + 0);
        float* err  = (float*)(base + 8);
        float* loss = (float*)(base + 16);
        float* u    = (float*)(base + 64);
        float* v    = (float*)(base + 64 + 8192);
        float* vden = (float*)(base + 64 + 8192 + 80000);

        fb_init<<<79, 256, 0, stream>>>(u, vden, done, err, loss);
        dim3 cgrid(20, 40);
        for (int t = 1; t <= 100; ++t) {
            fb_colpass<<<cgrid, 256, 0, stream>>>(M, u, vden, done);
            fb_finv<<<79, 256, 0, stream>>>(v, vden, done);
            fb_rowpass<<<ROWS_R, 256, 0, stream>>>(M, v, u, done);
            if (t == 1 || t == 51) {
                fb_colpass<<<cgrid, 256, 0, stream>>>(M, u, vden, done);
                fb_errfin<<<79, 256, 0, stream>>>(v, vden, err, done);
                fb_check<<<1, 64, 0, stream>>>(done, err);
            }
        }
        fb_loss<<<ROWS_R, 256, 0, stream>>>(M, u, v, loss);
        fb_writeout<<<1, 64, 0, stream>>>((float*)d_out, loss);
    }
}